// Round 1
// baseline (256.024 us; speedup 1.0000x reference)
//
#include <hip/hip_runtime.h>

// T_lv2: out [4,128,96,96]  = fold(gather(unfold(ref_lv2,3,1,1)))/9
// T_lv1: out [4,64,192,192] = fold(gather(unfold(ref_lv1,6,2,2)))/9
// Closed form: per output pixel, 9 neighbor patches, each a shifted read.

#define NINE_INV (1.0f / 9.0f)

__global__ __launch_bounds__(192) void t_lv2_kernel(
    const int* __restrict__ idx,      // [4, 9216]
    const float* __restrict__ ref,    // [4,128,96,96]
    float* __restrict__ out)          // [4,128,96,96]
{
    const int x = threadIdx.x;                      // 0..95
    const int y = blockIdx.x * 2 + threadIdx.y;     // 0..95
    const int b = blockIdx.y;
    const int c0 = blockIdx.z * 16;                 // 8 groups of 16 channels

    const int* idxb = idx + b * 9216;

    int   off[9];
    float msk[9];
#pragma unroll
    for (int i = 0; i < 3; ++i) {
#pragma unroll
        for (int j = 0; j < 3; ++j) {
            int oy = y - 1 + i, ox = x - 1 + j;
            bool pv = (oy >= 0) & (oy < 96) & (ox >= 0) & (ox < 96);
            int pi = pv ? (oy * 96 + ox) : 0;
            int jv = idxb[pi];
            int jy = jv / 96;
            int jx = jv - jy * 96;
            int ys = y + (jy - oy);
            int xs = x + (jx - ox);
            bool sv = pv & (ys >= 0) & (ys < 96) & (xs >= 0) & (xs < 96);
            off[i * 3 + j] = sv ? (ys * 96 + xs) : 0;
            msk[i * 3 + j] = sv ? NINE_INV : 0.0f;
        }
    }

    const float* rb = ref + ((size_t)b * 128 + c0) * 9216;
    float* ob = out + (((size_t)b * 128 + c0) * 96 + y) * 96 + x;
#pragma unroll 4
    for (int c = 0; c < 16; ++c) {
        const float* rc = rb + (size_t)c * 9216;
        float acc = 0.f;
#pragma unroll
        for (int p = 0; p < 9; ++p) acc += msk[p] * rc[off[p]];
        ob[(size_t)c * 9216] = acc;
    }
}

__global__ __launch_bounds__(192) void t_lv1_kernel(
    const int* __restrict__ idx,      // [4, 9216]
    const float* __restrict__ ref,    // [4,64,192,192]
    float* __restrict__ out)          // [4,64,192,192]
{
    const int x = threadIdx.x;        // 0..191
    const int y = blockIdx.x;         // 0..191
    const int b = blockIdx.y;
    const int c0 = blockIdx.z * 16;   // 4 groups of 16 channels

    const int* idxb = idx + b * 9216;

    const int oy0 = (y + 2) / 2 - 2;  // 3 contributing patch rows: oy0..oy0+2
    const int ox0 = (x + 2) / 2 - 2;

    int   off[9];
    float msk[9];
#pragma unroll
    for (int i = 0; i < 3; ++i) {
#pragma unroll
        for (int j = 0; j < 3; ++j) {
            int oy = oy0 + i, ox = ox0 + j;
            bool pv = (oy >= 0) & (oy < 96) & (ox >= 0) & (ox < 96);
            int pi = pv ? (oy * 96 + ox) : 0;
            int jv = idxb[pi];
            int jy = jv / 96;
            int jx = jv - jy * 96;
            int ys = y + 2 * (jy - oy);
            int xs = x + 2 * (jx - ox);
            bool sv = pv & (ys >= 0) & (ys < 192) & (xs >= 0) & (xs < 192);
            off[i * 3 + j] = sv ? (ys * 192 + xs) : 0;
            msk[i * 3 + j] = sv ? NINE_INV : 0.0f;
        }
    }

    const float* rb = ref + ((size_t)b * 64 + c0) * 36864;
    float* ob = out + (((size_t)b * 64 + c0) * 192 + y) * 192 + x;
#pragma unroll 4
    for (int c = 0; c < 16; ++c) {
        const float* rc = rb + (size_t)c * 36864;
        float acc = 0.f;
#pragma unroll
        for (int p = 0; p < 9; ++p) acc += msk[p] * rc[off[p]];
        ob[(size_t)c * 36864] = acc;
    }
}

extern "C" void kernel_launch(void* const* d_in, const int* in_sizes, int n_in,
                              void* d_out, int out_size, void* d_ws, size_t ws_size,
                              hipStream_t stream) {
    const int*   idx  = (const int*)d_in[0];   // R_lv2_star_arg [4,9216]
    // d_in[1] = lrsr_lv2 (only used for shape in reference)
    const float* ref1 = (const float*)d_in[2]; // ref_lv1 [4,64,192,192]
    const float* ref2 = (const float*)d_in[3]; // ref_lv2 [4,128,96,96]

    float* out2 = (float*)d_out;               // T_lv2 [4,128,96,96]
    float* out1 = out2 + (size_t)4 * 128 * 96 * 96; // T_lv1 [4,64,192,192]

    dim3 g2(48, 4, 8), b2(96, 2, 1);
    hipLaunchKernelGGL(t_lv2_kernel, g2, b2, 0, stream, idx, ref2, out2);

    dim3 g1(192, 4, 4), b1(192, 1, 1);
    hipLaunchKernelGGL(t_lv1_kernel, g1, b1, 0, stream, idx, ref1, out1);
}